// Round 9
// baseline (61.570 us; speedup 1.0000x reference)
//
#include <hip/hip_runtime.h>

// LengthRegulator: expand x[B,T,D] by integer durations into out[B,MAX_LEN,D],
// plus mel_len[B] = cumsum(duration)[:, -1].
// B=32, T=512, D=512, MAX_LEN=4096, durations in [0,10).
//
// R8: R7 with ONE change: plain cached stores instead of
// __builtin_nontemporal_store. Evidence: the harness's fillBufferAligned
// (plain stores) sustains 6.7-7.0 TB/s writing 1 GB; our nt-store kernel
// plateaus at ~5 TB/s across every work decomposition (R4/R6/R7 all
// 54.5-56.4 us). Theory: nt bypasses L2 write-combining; plain stores use
// the same L2 write-back path the fast fill uses.

typedef float f32x4 __attribute__((ext_vector_type(4)));
typedef int   i32x4 __attribute__((ext_vector_type(4)));

#define B_      32
#define T_      512
#define D_      512
#define MAXLEN_ 4096
#define BPB_    128                      // blocks per batch (4 tokens/block)
#define NBLK_   (B_ * BPB_)              // 4096 blocks

__global__ void lr_fused_kernel(const float* __restrict__ x,
                                const int* __restrict__ dur,
                                float* __restrict__ out,
                                float* __restrict__ mel_out) {
    const int gid  = blockIdx.x;
    const int b    = gid >> 7;               // / BPB_
    const int blk  = gid & (BPB_ - 1);
    const int wid  = threadIdx.x >> 6;       // wave id 0..3
    const int lane = threadIdx.x & 63;
    const int t    = blk * 4 + wid;          // wave-uniform token

    // ---- issue the row load FIRST (independent of the scan) ----
    const f32x4* row = (const f32x4*)(x + ((size_t)b * T_ + t) * D_);
    const f32x4 va = row[lane];
    const f32x4 vb = row[lane + 64];

    // ---- wave-redundant inclusive scan of duration[b][:] in registers ----
    const i32x4* src = (const i32x4*)(dur + b * T_);
    i32x4 a = src[lane * 2];
    i32x4 c = src[lane * 2 + 1];
    int v0 = a.x,      v1 = v0 + a.y, v2 = v1 + a.z, v3 = v2 + a.w;
    int v4 = v3 + c.x, v5 = v4 + c.y, v6 = v5 + c.z, v7 = v6 + c.w;
    int s = v7;
    #pragma unroll
    for (int d = 1; d < 64; d <<= 1) {
        int u = __shfl_up(s, d, 64);
        if (lane >= d) s += u;
    }
    const int off = s - v7;                  // exclusive prefix of this lane
    v0 += off; v1 += off; v2 += off; v3 += off;
    v4 += off; v5 += off; v6 += off; v7 += off;
    // lane l holds cum[8l .. 8l+7]

    const int mel = __shfl(v7, 63, 64);

    // ---- hi = cum[t], lo = cum[t-1] (t wave-uniform) ----
    const int e = t & 7;
    int sel = v0;
    sel = (e == 1) ? v1 : sel;  sel = (e == 2) ? v2 : sel;
    sel = (e == 3) ? v3 : sel;  sel = (e == 4) ? v4 : sel;
    sel = (e == 5) ? v5 : sel;  sel = (e == 6) ? v6 : sel;
    sel = (e == 7) ? v7 : sel;
    int hi = __shfl(sel, t >> 3, 64);
    int lo = 0;
    if (t > 0) {
        const int e2 = (t - 1) & 7;
        int sl = v0;
        sl = (e2 == 1) ? v1 : sl;  sl = (e2 == 2) ? v2 : sl;
        sl = (e2 == 3) ? v3 : sl;  sl = (e2 == 4) ? v4 : sl;
        sl = (e2 == 5) ? v5 : sl;  sl = (e2 == 6) ? v6 : sl;
        sl = (e2 == 7) ? v7 : sl;
        lo = __shfl(sl, (t - 1) >> 3, 64);
    }
    hi = min(hi, MAXLEN_);                   // robustness clamp
    lo = min(lo, MAXLEN_);

    // ---- expand: write the row to frames [lo, hi) ----
    f32x4* dst = (f32x4*)(out + ((size_t)b * MAXLEN_ + lo) * D_);
    for (int i = 0; i < hi - lo; ++i) {
        dst[i * 128 + lane]      = va;
        dst[i * 128 + lane + 64] = vb;
    }

    // ---- zero-fill: contiguous per-wave chunk of [mel, MAXLEN_) ----
    const int nz    = MAXLEN_ - mel;
    const int chunk = (nz + T_ - 1) >> 9;    // ceil(nz / 512)
    const int z0    = mel + t * chunk;
    const int z1    = min(z0 + chunk, MAXLEN_);
    const f32x4 z = {0.f, 0.f, 0.f, 0.f};
    for (int f = z0; f < z1; ++f) {
        f32x4* dz = (f32x4*)(out + ((size_t)b * MAXLEN_ + f) * D_);
        dz[lane]      = z;
        dz[lane + 64] = z;
    }

    if (blk == 0 && threadIdx.x == 0) mel_out[b] = (float)mel;
}

extern "C" void kernel_launch(void* const* d_in, const int* in_sizes, int n_in,
                              void* d_out, int out_size, void* d_ws, size_t ws_size,
                              hipStream_t stream) {
    const float* x   = (const float*)d_in[0];
    const int*   dur = (const int*)d_in[1];
    // d_in[2] is max_len (=4096), compile-time constant here.

    float* out     = (float*)d_out;
    float* mel_out = out + (size_t)B_ * MAXLEN_ * D_;   // tail: 32 elements

    lr_fused_kernel<<<NBLK_, 256, 0, stream>>>(x, dur, out, mel_out);
}

// Round 10
// 54.401 us; speedup vs baseline: 1.1318x; 1.1318x over previous
//
#include <hip/hip_runtime.h>

// LengthRegulator: expand x[B,T,D] by integer durations into out[B,MAX_LEN,D],
// plus mel_len[B] = cumsum(duration)[:, -1].
// B=32, T=512, D=512, MAX_LEN=4096, durations in [0,10).
//
// R9: revert to the best-measured config (R4, 54.5 us): fused single kernel,
// 2 tokens per 256-thread block, nontemporal stores (R8 proved plain stores
// cost +5-7 us), interleaved zero cover. Probes R5/R6/R7 (TPB=8+LDS map,
// wave-per-token, contiguous zero slabs) were all null-or-worse; R4's
// structure is the plateau winner. MAXLEN clamps kept (free, robust).

typedef float f32x4 __attribute__((ext_vector_type(4)));
typedef int   i32x4 __attribute__((ext_vector_type(4)));

#define B_      32
#define T_      512
#define D_      512
#define MAXLEN_ 4096
#define TPB_    2                        // tokens per block
#define NBLK_   (B_ * T_ / TPB_)         // 8192 blocks, 256 threads

__global__ void lr_fused_kernel(const float* __restrict__ x,
                                const int* __restrict__ dur,
                                float* __restrict__ out,
                                float* __restrict__ mel_out) {
    const int gid  = blockIdx.x;
    const int b    = gid >> 8;               // / (T_/TPB_) = 256
    const int t0   = (gid & 255) * TPB_;
    const int sub  = threadIdx.x >> 7;       // which token of the pair
    const int half = (threadIdx.x >> 6) & 1; // which wave within the 128-group
    const int lane = threadIdx.x & 63;
    const int t    = t0 + sub;               // wave-uniform

    // ---- wave-redundant inclusive scan of duration[b][:] in registers ----
    const i32x4* src = (const i32x4*)(dur + b * T_);
    i32x4 a = src[lane * 2];
    i32x4 c = src[lane * 2 + 1];
    int v0 = a.x,      v1 = v0 + a.y, v2 = v1 + a.z, v3 = v2 + a.w;
    int v4 = v3 + c.x, v5 = v4 + c.y, v6 = v5 + c.z, v7 = v6 + c.w;
    int s = v7;
    #pragma unroll
    for (int d = 1; d < 64; d <<= 1) {
        int u = __shfl_up(s, d, 64);
        if (lane >= d) s += u;
    }
    const int off = s - v7;                  // exclusive prefix of this lane
    v0 += off; v1 += off; v2 += off; v3 += off;
    v4 += off; v5 += off; v6 += off; v7 += off;
    // lane l holds cum[8l .. 8l+7] in v0..v7

    const int mel = __shfl(v7, 63, 64);

    // ---- extract hi = cum[t], lo = cum[t-1] (t is wave-uniform) ----
    int e = t & 7;
    int sel = v0;
    sel = (e == 1) ? v1 : sel;  sel = (e == 2) ? v2 : sel;
    sel = (e == 3) ? v3 : sel;  sel = (e == 4) ? v4 : sel;
    sel = (e == 5) ? v5 : sel;  sel = (e == 6) ? v6 : sel;
    sel = (e == 7) ? v7 : sel;
    int hi = __shfl(sel, t >> 3, 64);
    int lo = 0;
    if (t > 0) {
        int e2 = (t - 1) & 7;
        int sl = v0;
        sl = (e2 == 1) ? v1 : sl;  sl = (e2 == 2) ? v2 : sl;
        sl = (e2 == 3) ? v3 : sl;  sl = (e2 == 4) ? v4 : sl;
        sl = (e2 == 5) ? v5 : sl;  sl = (e2 == 6) ? v6 : sl;
        sl = (e2 == 7) ? v7 : sl;
        lo = __shfl(sl, (t - 1) >> 3, 64);
    }
    hi = min(hi, MAXLEN_);                   // robustness clamp
    lo = min(lo, MAXLEN_);

    // ---- expand: write x[b][t] to frames [lo, hi) ----
    const int fl = half * 64 + lane;         // float4 index in row, 0..127
    const int du = hi - lo;
    if (du > 0) {
        const f32x4 v = ((const f32x4*)(x + ((size_t)b * T_ + t) * D_))[fl];
        f32x4* dst = (f32x4*)(out + ((size_t)b * MAXLEN_ + lo) * D_) + fl;
        for (int i = 0; i < du; ++i)
            __builtin_nontemporal_store(v, dst + i * (D_ / 4));
    }

    // ---- zero-fill share: frames mel + t + 512k (exact disjoint cover) ----
    const f32x4 z = {0.f, 0.f, 0.f, 0.f};
    for (int f = mel + t; f < MAXLEN_; f += T_) {
        f32x4* dz = (f32x4*)(out + ((size_t)b * MAXLEN_ + f) * D_) + fl;
        __builtin_nontemporal_store(z, dz);
    }

    if (t == 0 && threadIdx.x == 0) mel_out[b] = (float)mel;
}

extern "C" void kernel_launch(void* const* d_in, const int* in_sizes, int n_in,
                              void* d_out, int out_size, void* d_ws, size_t ws_size,
                              hipStream_t stream) {
    const float* x   = (const float*)d_in[0];
    const int*   dur = (const int*)d_in[1];
    // d_in[2] is max_len (=4096), compile-time constant here.

    float* out     = (float*)d_out;
    float* mel_out = out + (size_t)B_ * MAXLEN_ * D_;   // tail: 32 elements

    lr_fused_kernel<<<NBLK_, 256, 0, stream>>>(x, dur, out, mel_out);
}